// Round 8
// baseline (3431.654 us; speedup 1.0000x reference)
//
#include <hip/hip_runtime.h>
#include <hip/hip_bf16.h>
#include <stdint.h>

typedef unsigned long long u64;
typedef unsigned int u32;
typedef unsigned short u16;

#define B_   4
#define C_   64
#define N_   8192
#define M_   2048
#define KNB  16
#define FLT_MAX_ 3.402823466e+38f
#define SMEM_SZ 86016   // 84KB: forces 1 block/CU (2x84 > 160KB) -> fps CUs
                        // never host active knn blocks (issue isolation)

__device__ __forceinline__ int clampN(int v) {
    return v < 0 ? 0 : (v > N_ - 1 ? N_ - 1 : v);
}

// ---------------- ws layout (bytes) — TOTAL 524288 ----------------
// idx_ws   : u16[B_*M_]       @ 0       (16384 B)
// nbr_ws   : u16[B_*M_*KNB]   @ 16384   (262144 B)
// pnorm_ws : float[B_*N_]     @ 278528  (131072 B)
// wt_ws    : float[448*64]    @ 409600  (114688 B)
// progress flags: u32[16] at start of out0 (overwritten by conv at the end;
// re-zeroed every replay by init_kernel — no stale-ws reliance).

__device__ __forceinline__ void pin4(float4& v) {
    asm volatile("" : "+v"(v.x), "+v"(v.y), "+v"(v.z), "+v"(v.w));
}

// DPP wave64 max -> returns wave max broadcast (via lane 63 readlane).
__device__ __forceinline__ float wave_fmax_dpp(float v) {
    float t;
    t = __int_as_float(__builtin_amdgcn_update_dpp(0, __float_as_int(v), 0x111, 0xf, 0xf, true)); v = fmaxf(v, t);
    t = __int_as_float(__builtin_amdgcn_update_dpp(0, __float_as_int(v), 0x112, 0xf, 0xf, true)); v = fmaxf(v, t);
    t = __int_as_float(__builtin_amdgcn_update_dpp(0, __float_as_int(v), 0x114, 0xf, 0xf, true)); v = fmaxf(v, t);
    t = __int_as_float(__builtin_amdgcn_update_dpp(0, __float_as_int(v), 0x118, 0xf, 0xf, true)); v = fmaxf(v, t);
    t = __int_as_float(__builtin_amdgcn_update_dpp(0, __float_as_int(v), 0x142, 0xa, 0xf, true)); v = fmaxf(v, t);
    t = __int_as_float(__builtin_amdgcn_update_dpp(0, __float_as_int(v), 0x143, 0xc, 0xf, true)); v = fmaxf(v, t);
    return __int_as_float(__builtin_amdgcn_readlane(__float_as_int(v), 63));
}

// np-exact FPS step (r7-r11: bit-exact 3-mul/2-add form, NO fma contraction).
#define FPS_STEP(PX, PY, PZ, DD, J)                                          \
    {                                                                        \
        float dx = __fsub_rn((PX), lx);                                      \
        float dy = __fsub_rn((PY), ly);                                      \
        float dz = __fsub_rn((PZ), lz);                                      \
        float d = __fadd_rn(__fadd_rn(__fmul_rn(dx, dx), __fmul_rn(dy, dy)), \
                            __fmul_rn(dz, dz));                              \
        float nd = fminf((DD), d);                                           \
        (DD) = nd;                                                           \
        bool gt = nd > fm;                                                   \
        fm = gt ? nd : fm;                                                   \
        fj = gt ? (J) : fj;                                                  \
        fx = gt ? (PX) : fx;                                                 \
        fy = gt ? (PY) : fy;                                                 \
        fz = gt ? (PZ) : fz;                                                 \
    }

__global__ void init_kernel(u32* __restrict__ flags) {
    if (threadIdx.x < 16) flags[threadIdx.x] = 0;
}

// ================== MEGA: fps + pnorm + wtrans + pipelined knn ==============
// ROUND 19/20: knn groups 0..62 hide under fps's 2ms shadow via spin-wait on
// a progress counter (released every 64 fps iters). Only group 63 (ready at
// fps end) stays on the critical path. fps reshaped to 4 blocks x 256thr x
// 32pts (identical total issue cycles, bit-identical math); knn body is r6
// VERBATIM behind the spin. Roles by block id: 0-3 fps, 4-131 pnorm,
// 132-243 wtrans, 244-499 knn.
__global__ __launch_bounds__(256, 1) void mega_kernel(
    const float* __restrict__ xyz, const float* __restrict__ x,
    const float* __restrict__ W0, const float* __restrict__ W1,
    const float* __restrict__ W2, u16* __restrict__ idx_ws,
    float* __restrict__ pnorm_ws, float* __restrict__ wt,
    float* __restrict__ out1, float* __restrict__ out2,
    u16* __restrict__ nbr_ws, u32* __restrict__ flags) {
    const int bid = blockIdx.x;
    const int tid = threadIdx.x;
    __shared__ __align__(16) char SM[SMEM_SZ];

    if (bid < 4) {
        // ---------------- fps (1 block per batch) + fused gather ----------
        const int b = bid;
        const int lane = tid & 63;
        const int w = tid >> 6;             // 4 waves
        const float* xb = xyz + b * 3 * N_;
        const int n0 = tid * 32;

        float4* red4 = (float4*)SM;          // [2][4]
        int*    redi = (int*)(SM + 128);     // [2][4]
        u16*    hist = (u16*)(SM + 160);     // [M_]

        float4 px[8], py[8], pz[8], dd[8];
#pragma unroll
        for (int j4 = 0; j4 < 8; ++j4) {
            px[j4] = *(const float4*)(xb + n0 + j4 * 4);
            py[j4] = *(const float4*)(xb + N_ + n0 + j4 * 4);
            pz[j4] = *(const float4*)(xb + 2 * N_ + n0 + j4 * 4);
            pin4(px[j4]); pin4(py[j4]); pin4(pz[j4]);
            dd[j4] = make_float4(FLT_MAX_, FLT_MAX_, FLT_MAX_, FLT_MAX_);
        }

        int cur = 0;
        float lx = xb[0], ly = xb[N_], lz = xb[2 * N_];
        if (tid == 0) { idx_ws[b * M_ + 0] = 0; hist[0] = 0; }

        for (int s = 1; s < M_; ++s) {
            float fm = -1.0f, fx = 0.f, fy = 0.f, fz = 0.f;
            int fj = 0;
#pragma unroll
            for (int j4 = 0; j4 < 8; ++j4) {
                FPS_STEP(px[j4].x, py[j4].x, pz[j4].x, dd[j4].x, j4 * 4 + 0);
                FPS_STEP(px[j4].y, py[j4].y, pz[j4].y, dd[j4].y, j4 * 4 + 1);
                FPS_STEP(px[j4].z, py[j4].z, pz[j4].z, dd[j4].z, j4 * 4 + 2);
                FPS_STEP(px[j4].w, py[j4].w, pz[j4].w, dd[j4].w, j4 * 4 + 3);
            }
            float wm = wave_fmax_dpp(fm);    // wave-uniform
            u64 bal = __ballot(fm == wm);    // >=1 bit set
            int winlane = (int)__ffsll(bal) - 1;
            const int par = s & 1;
            if (lane == winlane) {
                red4[(par << 2) + w] = make_float4(wm, fx, fy, fz);
                redi[(par << 2) + w] = n0 + fj;
            }
            __syncthreads();
            float4 p0 = red4[par << 2];
            float g = p0.x; float nlx = p0.y, nly = p0.z, nlz = p0.w;
            int ncur = redi[par << 2];
#pragma unroll
            for (int ww = 1; ww < 4; ++ww) {
                float4 p = red4[(par << 2) + ww];
                int id = redi[(par << 2) + ww];
                bool gt = p.x > g;           // strict: keeps first wave on ties
                g = gt ? p.x : g;
                nlx = gt ? p.y : nlx; nly = gt ? p.z : nly; nlz = gt ? p.w : nlz;
                ncur = gt ? id : ncur;
            }
            lx = nlx; ly = nly; lz = nlz; cur = ncur;
            if (tid == 0) {
                idx_ws[b * M_ + s] = (u16)cur; hist[s] = (u16)cur;
                if ((s & 63) == 63)   // amortized agent-release (L2 wb cost)
                    __hip_atomic_store(&flags[b], (u32)s, __ATOMIC_RELEASE,
                                       __HIP_MEMORY_SCOPE_AGENT);
            }
            // single barrier per iter: next iter writes red4[par^1]
        }

        __syncthreads();                     // hist complete
        for (int m = tid; m < M_; m += 256) {
            int idx = (int)hist[m];
            out2[b * M_ + m] = (float)idx;
            out1[(b * 3 + 0) * M_ + m] = xb[idx];
            out1[(b * 3 + 1) * M_ + m] = xb[N_ + idx];
            out1[(b * 3 + 2) * M_ + m] = xb[2 * N_ + idx];
        }
        return;
    }

    if (bid < 132) {
        // ---------------- pnorm: blocks 4..131 ----------------
        int gid = (bid - 4) * 256 + tid;     // 0..32767
        int bb = gid >> 13, n = gid & 8191;
        const float* xb = x + bb * C_ * N_ + n;
        float acc = 0.f;
#pragma unroll 16
        for (int c = 0; c < C_; ++c) { float v = xb[c * N_]; acc = fmaf(v, v, acc); }
        pnorm_ws[gid] = acc;
        __syncthreads();                     // drains block's stores
        if (tid == 0)
            __hip_atomic_fetch_add(&flags[4], 1u, __ATOMIC_RELEASE,
                                   __HIP_MEMORY_SCOPE_AGENT);
        return;
    }

    if (bid < 244) {
        // ---------------- wtrans: blocks 132..243 ----------------
        int e = (bid - 132) * 256 + tid;     // 0..28671
        if (e < 8192) {
            int i = e >> 6, o = e & 63;
            wt[e] = W0[o * 128 + i];
        } else if (e < 16384) {
            int e2 = e - 8192; int i = e2 >> 6, o = e2 & 63;
            wt[8192 + e2] = W1[o * 128 + i];
        } else {
            int e2 = e - 16384; int i = e2 >> 6, o = e2 & 63;
            wt[16384 + e2] = W2[o * 192 + i];
        }
        return;
    }

    // ---------------- knn: blocks 244..499 (r6 body + spin-wait) ----------
    {
        const int kid = bid - 244;
        const int b = kid >> 6;
        const int m0 = (kid & 63) * 32;

        float* pt    = (float*)SM;             // 64*68 floats (17408 B)
        float* spn   = (float*)(SM + 17408);   // 64 floats (256 B)
        u64*   lists = (u64*)(SM + 17664);     // 256*17 u64 (34816 B)

        if (tid == 0) {
            while (__hip_atomic_load(&flags[4], __ATOMIC_ACQUIRE,
                                     __HIP_MEMORY_SCOPE_AGENT) < 128u)
                __builtin_amdgcn_s_sleep(2);
            const u32 need = (u32)(m0 + 31);
            while (__hip_atomic_load(&flags[b], __ATOMIC_ACQUIRE,
                                     __HIP_MEMORY_SCOPE_AGENT) < need)
                __builtin_amdgcn_s_sleep(2);
        }
        __syncthreads();                       // release all waves; idx valid

        const int q = tid & 31, sub = tid >> 5;
        const int m = m0 + q;
        const float* xb = x + b * C_ * N_;
        const int self = clampN((int)idx_ws[b * M_ + m]);

        float4 qv[16];
#pragma unroll
        for (int c4 = 0; c4 < 16; ++c4) {
            qv[c4].x = xb[(c4 * 4 + 0) * N_ + self];
            qv[c4].y = xb[(c4 * 4 + 1) * N_ + self];
            qv[c4].z = xb[(c4 * 4 + 2) * N_ + self];
            qv[c4].w = xb[(c4 * 4 + 3) * N_ + self];
        }
        const float qn = pnorm_ws[b * N_ + self];

        u64* L = lists + tid * 17;
#pragma unroll
        for (int j = 0; j < 17; ++j) L[j] = ~0ULL;
        u64 worst = ~0ULL;

        for (int t = 0; t < N_ / 64; ++t) {
            const int nb0 = t * 64;
            __syncthreads();
#pragma unroll
            for (int r = 0; r < 4; ++r) {
                int e = tid + r * 256;         // 0..1023 float4 units
                int c = e >> 4, nq = e & 15;
                float4 v = *(const float4*)(xb + c * N_ + nb0 + nq * 4);
                const int cs = c ^ (nq << 2);  // bank swizzle (r17)
                pt[(nq * 4 + 0) * 68 + cs] = v.x;
                pt[(nq * 4 + 1) * 68 + cs] = v.y;
                pt[(nq * 4 + 2) * 68 + cs] = v.z;
                pt[(nq * 4 + 3) * 68 + cs] = v.w;
            }
            if (tid < 64) spn[tid] = pnorm_ws[b * N_ + nb0 + tid];
            __syncthreads();
#pragma unroll
            for (int pp = 0; pp < 8; ++pp) {
                int nl = sub * 8 + pp;
                const float* pvbase = pt + nl * 68;
                const int rsw = (nl >> 2) << 2;
                float a0 = 0.f, a1 = 0.f, a2 = 0.f, a3 = 0.f;
#pragma unroll
                for (int c4 = 0; c4 < 16; ++c4) {
                    float4 p = *(const float4*)(pvbase + (((c4 << 2) ^ rsw)));
                    a0 = fmaf(qv[c4].x, p.x, a0);
                    a1 = fmaf(qv[c4].y, p.y, a1);
                    a2 = fmaf(qv[c4].z, p.z, a2);
                    a3 = fmaf(qv[c4].w, p.w, a3);
                }
                float dot = (a0 + a1) + (a2 + a3);
                float d = qn + spn[nl] - 2.0f * dot;
                u32 db = __float_as_uint(d);
                db = (db & 0x80000000u) ? ~db : (db | 0x80000000u);
                u64 key = ((u64)db << 32) | (u32)(nb0 + nl);
                if (key < worst) {
                    int j = 16;
                    while (j > 0 && L[j - 1] > key) { L[j] = L[j - 1]; --j; }
                    L[j] = key;
                    worst = L[16];
                }
            }
        }
        __syncthreads();
        if (tid < 32) {
            int pos[8];
#pragma unroll
            for (int s2 = 0; s2 < 8; ++s2) pos[s2] = 0;
            u16* outp = nbr_ws + (b * M_ + m0 + tid) * KNB;
            for (int r = 0; r < 17; ++r) {
                u64 best = ~0ULL; int bs = 0;
#pragma unroll
                for (int s2 = 0; s2 < 8; ++s2) {
                    u64 k2 = (pos[s2] < 17) ? lists[(tid + 32 * s2) * 17 + pos[s2]] : ~0ULL;
                    if (k2 < best) { best = k2; bs = s2; }
                }
#pragma unroll
                for (int s2 = 0; s2 < 8; ++s2) pos[s2] += (s2 == bs) ? 1 : 0;
                if (r > 0) outp[r - 1] = (u16)clampN((int)(best & 0xFFFFFFFFu));
            }
        }
    }
}

// =================== fused edge-conv x3 + k-maxpool (r6 verbatim) ==========
__device__ __forceinline__ void mm_tile(float a[4][4], const float* __restrict__ w,
                                        const float* __restrict__ s, int ni) {
#pragma unroll 8
    for (int i = 0; i < ni; ++i) {
        const float4 w4 = *(const float4*)(w + i * 64);
        const float4 e4 = *(const float4*)(s + i * 64);
        a[0][0] = fmaf(w4.x, e4.x, a[0][0]);
        a[0][1] = fmaf(w4.x, e4.y, a[0][1]);
        a[0][2] = fmaf(w4.x, e4.z, a[0][2]);
        a[0][3] = fmaf(w4.x, e4.w, a[0][3]);
        a[1][0] = fmaf(w4.y, e4.x, a[1][0]);
        a[1][1] = fmaf(w4.y, e4.y, a[1][1]);
        a[1][2] = fmaf(w4.y, e4.z, a[1][2]);
        a[1][3] = fmaf(w4.y, e4.w, a[1][3]);
        a[2][0] = fmaf(w4.z, e4.x, a[2][0]);
        a[2][1] = fmaf(w4.z, e4.y, a[2][1]);
        a[2][2] = fmaf(w4.z, e4.z, a[2][2]);
        a[2][3] = fmaf(w4.z, e4.w, a[2][3]);
        a[3][0] = fmaf(w4.w, e4.x, a[3][0]);
        a[3][1] = fmaf(w4.w, e4.y, a[3][1]);
        a[3][2] = fmaf(w4.w, e4.z, a[3][2]);
        a[3][3] = fmaf(w4.w, e4.w, a[3][3]);
    }
}

__global__ __launch_bounds__(256) void conv_kernel(const float* __restrict__ x,
                                                   const u16* __restrict__ idx_ws,
                                                   const u16* __restrict__ nbr_ws,
                                                   const float* __restrict__ wt,
                                                   const float* __restrict__ bias0,
                                                   const float* __restrict__ bias1,
                                                   const float* __restrict__ bias2,
                                                   float* __restrict__ out0) {
    __shared__ float E[128 * 64];    // rows 0..63 center; 64..127: nd -> h1 -> h2
    __shared__ float H0[64 * 64];

    const int tid = threadIdx.x;
    const int b = blockIdx.x >> 9;
    const int m0 = (blockIdx.x & 511) * 4;
    const float* xb = x + b * C_ * N_;

    {   // stage edge tile
        const int col = tid & 63;
        const int half = tid >> 6;
        const int m = m0 + (col >> 4);
        const int k = col & 15;
        const int selfm = clampN((int)idx_ws[b * M_ + m]);
        const int nbr = clampN((int)nbr_ws[(b * M_ + m) * KNB + k]);
#pragma unroll
        for (int c2 = 0; c2 < 16; ++c2) {
            int c = half * 16 + c2;
            float ctr = xb[c * N_ + selfm];
            float nb = xb[c * N_ + nbr];
            E[c * 64 + col] = ctr;
            E[(64 + c) * 64 + col] = __fsub_rn(nb, ctr);
        }
    }
    __syncthreads();

    const int o0 = (tid >> 4) * 4;
    const int c0 = (tid & 15) * 4;
    float a[4][4];

    {   // conv0 -> H0
        float4 bb = *(const float4*)(bias0 + o0);
        a[0][0] = a[0][1] = a[0][2] = a[0][3] = bb.x;
        a[1][0] = a[1][1] = a[1][2] = a[1][3] = bb.y;
        a[2][0] = a[2][1] = a[2][2] = a[2][3] = bb.z;
        a[3][0] = a[3][1] = a[3][2] = a[3][3] = bb.w;
        mm_tile(a, wt + o0, E + c0, 128);
#pragma unroll
        for (int oo = 0; oo < 4; ++oo) {
            float4 v = make_float4(fmaxf(a[oo][0], 0.f), fmaxf(a[oo][1], 0.f),
                                   fmaxf(a[oo][2], 0.f), fmaxf(a[oo][3], 0.f));
            *(float4*)(H0 + (o0 + oo) * 64 + c0) = v;
        }
    }
    __syncthreads();

    {   // conv1 -> h1 into E rows 64..127 (nd dead after conv0)
        float4 bb = *(const float4*)(bias1 + o0);
        a[0][0] = a[0][1] = a[0][2] = a[0][3] = bb.x;
        a[1][0] = a[1][1] = a[1][2] = a[1][3] = bb.y;
        a[2][0] = a[2][1] = a[2][2] = a[2][3] = bb.z;
        a[3][0] = a[3][1] = a[3][2] = a[3][3] = bb.w;
        mm_tile(a, wt + 8192 + o0, H0 + c0, 64);
        mm_tile(a, wt + 8192 + 64 * 64 + o0, E + c0, 64);
#pragma unroll
        for (int oo = 0; oo < 4; ++oo) {
            float4 v = make_float4(fmaxf(a[oo][0], 0.f), fmaxf(a[oo][1], 0.f),
                                   fmaxf(a[oo][2], 0.f), fmaxf(a[oo][3], 0.f));
            *(float4*)(E + (64 + o0 + oo) * 64 + c0) = v;
        }
    }
    __syncthreads();

    {   // conv2 (no relu), result held in regs until h1 maxpool done
        float4 bb = *(const float4*)(bias2 + o0);
        a[0][0] = a[0][1] = a[0][2] = a[0][3] = bb.x;
        a[1][0] = a[1][1] = a[1][2] = a[1][3] = bb.y;
        a[2][0] = a[2][1] = a[2][2] = a[2][3] = bb.z;
        a[3][0] = a[3][1] = a[3][2] = a[3][3] = bb.w;
        mm_tile(a, wt + 16384 + o0, E + 64 * 64 + c0, 64);
        mm_tile(a, wt + 16384 + 64 * 64 + o0, H0 + c0, 64);
        mm_tile(a, wt + 16384 + 128 * 64 + o0, E + c0, 64);
    }

    // maxpool A: ch 64..255 = [h1, h0, center]
#pragma unroll
    for (int r = 1; r < 4; ++r) {
        int e = tid + r * 256;
        int ch = e >> 2, mloc = e & 3;
        int colb = mloc * 16;
        float v;
        if (ch < 128) {
            const float* row = E + (64 + (ch - 64)) * 64 + colb;
            v = row[0];
#pragma unroll
            for (int k = 1; k < 16; ++k) v = fmaxf(v, row[k]);
        } else if (ch < 192) {
            const float* row = H0 + (ch - 128) * 64 + colb;
            v = row[0];
#pragma unroll
            for (int k = 1; k < 16; ++k) v = fmaxf(v, row[k]);
        } else {
            v = E[(ch - 192) * 64 + colb];
        }
        out0[((b * 256 + ch) << 11) + m0 + mloc] = v;
    }
    __syncthreads();

    {   // write h2 over h1 rows
#pragma unroll
        for (int oo = 0; oo < 4; ++oo) {
            float4 v = make_float4(a[oo][0], a[oo][1], a[oo][2], a[oo][3]);
            *(float4*)(E + (64 + o0 + oo) * 64 + c0) = v;
        }
    }
    __syncthreads();

    {   // maxpool B: ch 0..63 = h2
        int ch = tid >> 2, mloc = tid & 3;
        int colb = mloc * 16;
        const float* row = E + (64 + ch) * 64 + colb;
        float v = row[0];
#pragma unroll
        for (int k = 1; k < 16; ++k) v = fmaxf(v, row[k]);
        out0[((b * 256 + ch) << 11) + m0 + mloc] = v;
    }
}

extern "C" void kernel_launch(void* const* d_in, const int* in_sizes, int n_in,
                              void* d_out, int out_size, void* d_ws, size_t ws_size,
                              hipStream_t stream) {
    const float* x   = (const float*)d_in[0];
    const float* xyz = (const float*)d_in[1];
    const float* W0  = (const float*)d_in[2];
    const float* b0  = (const float*)d_in[3];
    const float* W1  = (const float*)d_in[4];
    const float* b1  = (const float*)d_in[5];
    const float* W2  = (const float*)d_in[6];
    const float* b2  = (const float*)d_in[7];

    float* out  = (float*)d_out;                 // FLOAT32 output buffer
    float* out0 = out;                           // y: 4*256*2048
    float* out1 = out + 4 * 256 * 2048;          // sampled_xyz: 4*3*2048
    float* out2 = out1 + 4 * 3 * 2048;           // sampled_idx (f32): 4*2048
    u32*   flags = (u32*)out0;                   // progress[4] + pnorm_done

    char* ws = (char*)d_ws;
    u16*   idx_ws   = (u16*)ws;                  // 16384 B
    u16*   nbr_ws   = (u16*)(ws + 16384);        // 262144 B
    float* pnorm_ws = (float*)(ws + 278528);     // 131072 B
    float* wt_ws    = (float*)(ws + 409600);     // 114688 B

    init_kernel<<<1, 64, 0, stream>>>(flags);
    mega_kernel<<<500, 256, 0, stream>>>(xyz, x, W0, W1, W2,
                                         idx_ws, pnorm_ws, wt_ws,
                                         out1, out2, nbr_ws, flags);
    conv_kernel<<<2048, 256, 0, stream>>>(x, idx_ws, nbr_ws, wt_ws,
                                          b0, b1, b2, out0);
}

// Round 9
// 2853.707 us; speedup vs baseline: 1.2025x; 1.2025x over previous
//
#include <hip/hip_runtime.h>
#include <hip/hip_bf16.h>
#include <stdint.h>

typedef unsigned long long u64;
typedef unsigned int u32;
typedef unsigned short u16;

#define B_   4
#define C_   64
#define N_   8192
#define M_   2048
#define KNB  16
#define FLT_MAX_ 3.402823466e+38f
#define SMEM_SZ 87296   // 17408(pt)+256(spn)+69632(lists); >80KB -> 1 block/CU

__device__ __forceinline__ int clampN(int v) {
    return v < 0 ? 0 : (v > N_ - 1 ? N_ - 1 : v);
}

// ---------------- ws layout (bytes) — TOTAL 524288 ----------------
// idx_ws   : u16[B_*M_]       @ 0       (16384 B)
// nbr_ws   : u16[B_*M_*KNB]   @ 16384   (262144 B)
// pnorm_ws : float[B_*N_]     @ 278528  (131072 B)
// wt_ws    : float[448*64]    @ 409600  (114688 B)
// progress flags: u32[16] at start of out0 (conv overwrites later; re-zeroed
// every replay by init_kernel).

__device__ __forceinline__ void pin4(float4& v) {
    asm volatile("" : "+v"(v.x), "+v"(v.y), "+v"(v.z), "+v"(v.w));
}

// DPP wave64 max -> returns wave max broadcast (via lane 63 readlane).
__device__ __forceinline__ float wave_fmax_dpp(float v) {
    float t;
    t = __int_as_float(__builtin_amdgcn_update_dpp(0, __float_as_int(v), 0x111, 0xf, 0xf, true)); v = fmaxf(v, t);
    t = __int_as_float(__builtin_amdgcn_update_dpp(0, __float_as_int(v), 0x112, 0xf, 0xf, true)); v = fmaxf(v, t);
    t = __int_as_float(__builtin_amdgcn_update_dpp(0, __float_as_int(v), 0x114, 0xf, 0xf, true)); v = fmaxf(v, t);
    t = __int_as_float(__builtin_amdgcn_update_dpp(0, __float_as_int(v), 0x118, 0xf, 0xf, true)); v = fmaxf(v, t);
    t = __int_as_float(__builtin_amdgcn_update_dpp(0, __float_as_int(v), 0x142, 0xa, 0xf, true)); v = fmaxf(v, t);
    t = __int_as_float(__builtin_amdgcn_update_dpp(0, __float_as_int(v), 0x143, 0xc, 0xf, true)); v = fmaxf(v, t);
    return __int_as_float(__builtin_amdgcn_readlane(__float_as_int(v), 63));
}

// np-exact FPS step (r7-r11: bit-exact 3-mul/2-add form, NO fma contraction).
#define FPS_STEP(PX, PY, PZ, DD, J)                                          \
    {                                                                        \
        float dx = __fsub_rn((PX), lx);                                      \
        float dy = __fsub_rn((PY), ly);                                      \
        float dz = __fsub_rn((PZ), lz);                                      \
        float d = __fadd_rn(__fadd_rn(__fmul_rn(dx, dx), __fmul_rn(dy, dy)), \
                            __fmul_rn(dz, dz));                              \
        float nd = fminf((DD), d);                                           \
        (DD) = nd;                                                           \
        bool gt = nd > fm;                                                   \
        fm = gt ? nd : fm;                                                   \
        fj = gt ? (J) : fj;                                                  \
        fx = gt ? (PX) : fx;                                                 \
        fy = gt ? (PY) : fy;                                                 \
        fz = gt ? (PZ) : fz;                                                 \
    }

__global__ void init_kernel(u32* __restrict__ flags) {
    if (threadIdx.x < 16) flags[threadIdx.x] = 0;
}

// ================== MEGA: fps + pnorm + wtrans + pipelined knn ==============
// ROUND 21: r8 post-mortem — pipeline machinery worked (correctness held,
// knn hid under fps) but fps's 256thr x 32pt reshape ran at 1 wave/SIMD
// with a 32-deep serial select chain -> latency-exposed, ~3300us. Fix:
// mega at 512 threads; fps blocks use the r0 body VERBATIM (512x16pt,
// 2 waves/SIMD, proven 2010us); knn upgraded to 16 sublists x 4pts (all
// 512 threads compute; same top-17 after merge — keys unique). Roles:
// 0-3 fps, 4-67 pnorm, 68-123 wtrans, 124-379 knn.
__global__ __launch_bounds__(512, 2) void mega_kernel(
    const float* __restrict__ xyz, const float* __restrict__ x,
    const float* __restrict__ W0, const float* __restrict__ W1,
    const float* __restrict__ W2, u16* __restrict__ idx_ws,
    float* __restrict__ pnorm_ws, float* __restrict__ wt,
    float* __restrict__ out1, float* __restrict__ out2,
    u16* __restrict__ nbr_ws, u32* __restrict__ flags) {
    const int bid = blockIdx.x;
    const int tid = threadIdx.x;
    __shared__ __align__(16) char SM[SMEM_SZ];

    if (bid < 4) {
        // ---------------- fps (r0 body) + hist + fused gather -------------
        const int b = bid;
        const int lane = tid & 63;
        const int w = tid >> 6;             // 8 waves
        const float* xb = xyz + b * 3 * N_;
        const int n0 = tid * 16;

        float4* red4 = (float4*)SM;          // [2][8] (256 B)
        int*    redi = (int*)(SM + 256);     // [2][8] (64 B)
        u16*    hist = (u16*)(SM + 320);     // [M_] (4096 B)

        float4 px[4], py[4], pz[4], dd[4];
#pragma unroll
        for (int j4 = 0; j4 < 4; ++j4) {
            px[j4] = *(const float4*)(xb + n0 + j4 * 4);
            py[j4] = *(const float4*)(xb + N_ + n0 + j4 * 4);
            pz[j4] = *(const float4*)(xb + 2 * N_ + n0 + j4 * 4);
            pin4(px[j4]); pin4(py[j4]); pin4(pz[j4]);
            dd[j4] = make_float4(FLT_MAX_, FLT_MAX_, FLT_MAX_, FLT_MAX_);
        }

        int cur = 0;
        float lx = xb[0], ly = xb[N_], lz = xb[2 * N_];
        if (tid == 0) { idx_ws[b * M_ + 0] = 0; hist[0] = 0; }

        for (int s = 1; s < M_; ++s) {
            float fm = -1.0f, fx = 0.f, fy = 0.f, fz = 0.f;
            int fj = 0;
#pragma unroll
            for (int j4 = 0; j4 < 4; ++j4) {
                FPS_STEP(px[j4].x, py[j4].x, pz[j4].x, dd[j4].x, j4 * 4 + 0);
                FPS_STEP(px[j4].y, py[j4].y, pz[j4].y, dd[j4].y, j4 * 4 + 1);
                FPS_STEP(px[j4].z, py[j4].z, pz[j4].z, dd[j4].z, j4 * 4 + 2);
                FPS_STEP(px[j4].w, py[j4].w, pz[j4].w, dd[j4].w, j4 * 4 + 3);
            }
            float wm = wave_fmax_dpp(fm);    // wave-uniform
            u64 bal = __ballot(fm == wm);    // >=1 bit set
            int winlane = (int)__ffsll(bal) - 1;
            const int par = s & 1;
            if (lane == winlane) {
                red4[(par << 3) + w] = make_float4(wm, fx, fy, fz);
                redi[(par << 3) + w] = n0 + fj;
            }
            __syncthreads();
            float4 p0 = red4[par << 3];
            float g = p0.x; float nlx = p0.y, nly = p0.z, nlz = p0.w;
            int ncur = redi[par << 3];
#pragma unroll
            for (int ww = 1; ww < 8; ++ww) {
                float4 p = red4[(par << 3) + ww];
                int id = redi[(par << 3) + ww];
                bool gt = p.x > g;           // strict: keeps first wave on ties
                g = gt ? p.x : g;
                nlx = gt ? p.y : nlx; nly = gt ? p.z : nly; nlz = gt ? p.w : nlz;
                ncur = gt ? id : ncur;
            }
            lx = nlx; ly = nly; lz = nlz; cur = ncur;
            if (tid == 0) {
                idx_ws[b * M_ + s] = (u16)cur; hist[s] = (u16)cur;
                if ((s & 63) == 63)   // amortized agent-release
                    __hip_atomic_store(&flags[b], (u32)s, __ATOMIC_RELEASE,
                                       __HIP_MEMORY_SCOPE_AGENT);
            }
            // single barrier per iter: next iter writes red4[par^1]
        }

        __syncthreads();                     // hist complete
        for (int m = tid; m < M_; m += 512) {
            int idx = (int)hist[m];
            out2[b * M_ + m] = (float)idx;
            out1[(b * 3 + 0) * M_ + m] = xb[idx];
            out1[(b * 3 + 1) * M_ + m] = xb[N_ + idx];
            out1[(b * 3 + 2) * M_ + m] = xb[2 * N_ + idx];
        }
        return;
    }

    if (bid < 68) {
        // ---------------- pnorm: blocks 4..67 ----------------
        int gid = (bid - 4) * 512 + tid;     // 0..32767
        int bb = gid >> 13, n = gid & 8191;
        const float* xb = x + bb * C_ * N_ + n;
        float acc = 0.f;
#pragma unroll 16
        for (int c = 0; c < C_; ++c) { float v = xb[c * N_]; acc = fmaf(v, v, acc); }
        pnorm_ws[gid] = acc;
        __syncthreads();                     // own stores drained (vmcnt0)
        if (tid == 0)
            __hip_atomic_fetch_add(&flags[4], 1u, __ATOMIC_RELEASE,
                                   __HIP_MEMORY_SCOPE_AGENT);
        return;
    }

    if (bid < 124) {
        // ---------------- wtrans: blocks 68..123 ----------------
        int e = (bid - 68) * 512 + tid;      // 0..28671
        if (e < 8192) {
            int i = e >> 6, o = e & 63;
            wt[e] = W0[o * 128 + i];
        } else if (e < 16384) {
            int e2 = e - 8192; int i = e2 >> 6, o = e2 & 63;
            wt[8192 + e2] = W1[o * 128 + i];
        } else {
            int e2 = e - 16384; int i = e2 >> 6, o = e2 & 63;
            wt[16384 + e2] = W2[o * 192 + i];
        }
        return;
    }

    // ------------- knn: blocks 124..379 (16 sublists x 4 pts, 512 thr) -----
    {
        const int kid = bid - 124;
        const int b = kid >> 6;
        const int m0 = (kid & 63) * 32;

        float* pt    = (float*)SM;             // 64*68 floats (17408 B)
        float* spn   = (float*)(SM + 17408);   // 64 floats (256 B)
        u64*   lists = (u64*)(SM + 17664);     // 512*17 u64 (69632 B)

        if (tid == 0) {
            while (__hip_atomic_load(&flags[4], __ATOMIC_ACQUIRE,
                                     __HIP_MEMORY_SCOPE_AGENT) < 64u)
                __builtin_amdgcn_s_sleep(2);
            const u32 need = (u32)(m0 + 31);
            while (__hip_atomic_load(&flags[b], __ATOMIC_ACQUIRE,
                                     __HIP_MEMORY_SCOPE_AGENT) < need)
                __builtin_amdgcn_s_sleep(2);
        }
        __syncthreads();                       // idx/pnorm valid for this block

        const int q = tid & 31, sub = tid >> 5;   // sub 0..15
        const int m = m0 + q;
        const float* xb = x + b * C_ * N_;
        const int self = clampN((int)idx_ws[b * M_ + m]);

        float4 qv[16];
#pragma unroll
        for (int c4 = 0; c4 < 16; ++c4) {
            qv[c4].x = xb[(c4 * 4 + 0) * N_ + self];
            qv[c4].y = xb[(c4 * 4 + 1) * N_ + self];
            qv[c4].z = xb[(c4 * 4 + 2) * N_ + self];
            qv[c4].w = xb[(c4 * 4 + 3) * N_ + self];
        }
        const float qn = pnorm_ws[b * N_ + self];

        u64* L = lists + tid * 17;
#pragma unroll
        for (int j = 0; j < 17; ++j) L[j] = ~0ULL;
        u64 worst = ~0ULL;

        for (int t = 0; t < N_ / 64; ++t) {
            const int nb0 = t * 64;
            __syncthreads();
#pragma unroll
            for (int r = 0; r < 2; ++r) {
                int e = tid + r * 512;         // 0..1023 float4 units
                int c = e >> 4, nq = e & 15;
                float4 v = *(const float4*)(xb + c * N_ + nb0 + nq * 4);
                const int cs = c ^ (nq << 2);  // bank swizzle (r17)
                pt[(nq * 4 + 0) * 68 + cs] = v.x;
                pt[(nq * 4 + 1) * 68 + cs] = v.y;
                pt[(nq * 4 + 2) * 68 + cs] = v.z;
                pt[(nq * 4 + 3) * 68 + cs] = v.w;
            }
            if (tid < 64) spn[tid] = pnorm_ws[b * N_ + nb0 + tid];
            __syncthreads();
#pragma unroll
            for (int pp = 0; pp < 4; ++pp) {
                int nl = sub * 4 + pp;
                const float* pvbase = pt + nl * 68;
                const int rsw = (nl >> 2) << 2;
                float a0 = 0.f, a1 = 0.f, a2 = 0.f, a3 = 0.f;
#pragma unroll
                for (int c4 = 0; c4 < 16; ++c4) {
                    float4 p = *(const float4*)(pvbase + (((c4 << 2) ^ rsw)));
                    a0 = fmaf(qv[c4].x, p.x, a0);
                    a1 = fmaf(qv[c4].y, p.y, a1);
                    a2 = fmaf(qv[c4].z, p.z, a2);
                    a3 = fmaf(qv[c4].w, p.w, a3);
                }
                float dot = (a0 + a1) + (a2 + a3);
                float d = qn + spn[nl] - 2.0f * dot;
                u32 db = __float_as_uint(d);
                db = (db & 0x80000000u) ? ~db : (db | 0x80000000u);
                u64 key = ((u64)db << 32) | (u32)(nb0 + nl);
                if (key < worst) {
                    int j = 16;
                    while (j > 0 && L[j - 1] > key) { L[j] = L[j - 1]; --j; }
                    L[j] = key;
                    worst = L[16];
                }
            }
        }
        __syncthreads();
        if (tid < 32) {
            int pos[16];
#pragma unroll
            for (int s2 = 0; s2 < 16; ++s2) pos[s2] = 0;
            u16* outp = nbr_ws + (b * M_ + m0 + tid) * KNB;
            for (int r = 0; r < 17; ++r) {
                u64 best = ~0ULL; int bs = 0;
#pragma unroll
                for (int s2 = 0; s2 < 16; ++s2) {
                    u64 k2 = (pos[s2] < 17) ? lists[(tid + 32 * s2) * 17 + pos[s2]] : ~0ULL;
                    if (k2 < best) { best = k2; bs = s2; }
                }
#pragma unroll
                for (int s2 = 0; s2 < 16; ++s2) pos[s2] += (s2 == bs) ? 1 : 0;
                if (r > 0) outp[r - 1] = (u16)clampN((int)(best & 0xFFFFFFFFu));
            }
        }
    }
}

// =================== fused edge-conv x3 + k-maxpool (r6 verbatim) ==========
__device__ __forceinline__ void mm_tile(float a[4][4], const float* __restrict__ w,
                                        const float* __restrict__ s, int ni) {
#pragma unroll 8
    for (int i = 0; i < ni; ++i) {
        const float4 w4 = *(const float4*)(w + i * 64);
        const float4 e4 = *(const float4*)(s + i * 64);
        a[0][0] = fmaf(w4.x, e4.x, a[0][0]);
        a[0][1] = fmaf(w4.x, e4.y, a[0][1]);
        a[0][2] = fmaf(w4.x, e4.z, a[0][2]);
        a[0][3] = fmaf(w4.x, e4.w, a[0][3]);
        a[1][0] = fmaf(w4.y, e4.x, a[1][0]);
        a[1][1] = fmaf(w4.y, e4.y, a[1][1]);
        a[1][2] = fmaf(w4.y, e4.z, a[1][2]);
        a[1][3] = fmaf(w4.y, e4.w, a[1][3]);
        a[2][0] = fmaf(w4.z, e4.x, a[2][0]);
        a[2][1] = fmaf(w4.z, e4.y, a[2][1]);
        a[2][2] = fmaf(w4.z, e4.z, a[2][2]);
        a[2][3] = fmaf(w4.z, e4.w, a[2][3]);
        a[3][0] = fmaf(w4.w, e4.x, a[3][0]);
        a[3][1] = fmaf(w4.w, e4.y, a[3][1]);
        a[3][2] = fmaf(w4.w, e4.z, a[3][2]);
        a[3][3] = fmaf(w4.w, e4.w, a[3][3]);
    }
}

__global__ __launch_bounds__(256) void conv_kernel(const float* __restrict__ x,
                                                   const u16* __restrict__ idx_ws,
                                                   const u16* __restrict__ nbr_ws,
                                                   const float* __restrict__ wt,
                                                   const float* __restrict__ bias0,
                                                   const float* __restrict__ bias1,
                                                   const float* __restrict__ bias2,
                                                   float* __restrict__ out0) {
    __shared__ float E[128 * 64];    // rows 0..63 center; 64..127: nd -> h1 -> h2
    __shared__ float H0[64 * 64];

    const int tid = threadIdx.x;
    const int b = blockIdx.x >> 9;
    const int m0 = (blockIdx.x & 511) * 4;
    const float* xb = x + b * C_ * N_;

    {   // stage edge tile
        const int col = tid & 63;
        const int half = tid >> 6;
        const int m = m0 + (col >> 4);
        const int k = col & 15;
        const int selfm = clampN((int)idx_ws[b * M_ + m]);
        const int nbr = clampN((int)nbr_ws[(b * M_ + m) * KNB + k]);
#pragma unroll
        for (int c2 = 0; c2 < 16; ++c2) {
            int c = half * 16 + c2;
            float ctr = xb[c * N_ + selfm];
            float nb = xb[c * N_ + nbr];
            E[c * 64 + col] = ctr;
            E[(64 + c) * 64 + col] = __fsub_rn(nb, ctr);
        }
    }
    __syncthreads();

    const int o0 = (tid >> 4) * 4;
    const int c0 = (tid & 15) * 4;
    float a[4][4];

    {   // conv0 -> H0
        float4 bb = *(const float4*)(bias0 + o0);
        a[0][0] = a[0][1] = a[0][2] = a[0][3] = bb.x;
        a[1][0] = a[1][1] = a[1][2] = a[1][3] = bb.y;
        a[2][0] = a[2][1] = a[2][2] = a[2][3] = bb.z;
        a[3][0] = a[3][1] = a[3][2] = a[3][3] = bb.w;
        mm_tile(a, wt + o0, E + c0, 128);
#pragma unroll
        for (int oo = 0; oo < 4; ++oo) {
            float4 v = make_float4(fmaxf(a[oo][0], 0.f), fmaxf(a[oo][1], 0.f),
                                   fmaxf(a[oo][2], 0.f), fmaxf(a[oo][3], 0.f));
            *(float4*)(H0 + (o0 + oo) * 64 + c0) = v;
        }
    }
    __syncthreads();

    {   // conv1 -> h1 into E rows 64..127 (nd dead after conv0)
        float4 bb = *(const float4*)(bias1 + o0);
        a[0][0] = a[0][1] = a[0][2] = a[0][3] = bb.x;
        a[1][0] = a[1][1] = a[1][2] = a[1][3] = bb.y;
        a[2][0] = a[2][1] = a[2][2] = a[2][3] = bb.z;
        a[3][0] = a[3][1] = a[3][2] = a[3][3] = bb.w;
        mm_tile(a, wt + 8192 + o0, H0 + c0, 64);
        mm_tile(a, wt + 8192 + 64 * 64 + o0, E + c0, 64);
#pragma unroll
        for (int oo = 0; oo < 4; ++oo) {
            float4 v = make_float4(fmaxf(a[oo][0], 0.f), fmaxf(a[oo][1], 0.f),
                                   fmaxf(a[oo][2], 0.f), fmaxf(a[oo][3], 0.f));
            *(float4*)(E + (64 + o0 + oo) * 64 + c0) = v;
        }
    }
    __syncthreads();

    {   // conv2 (no relu), result held in regs until h1 maxpool done
        float4 bb = *(const float4*)(bias2 + o0);
        a[0][0] = a[0][1] = a[0][2] = a[0][3] = bb.x;
        a[1][0] = a[1][1] = a[1][2] = a[1][3] = bb.y;
        a[2][0] = a[2][1] = a[2][2] = a[2][3] = bb.z;
        a[3][0] = a[3][1] = a[3][2] = a[3][3] = bb.w;
        mm_tile(a, wt + 16384 + o0, E + 64 * 64 + c0, 64);
        mm_tile(a, wt + 16384 + 64 * 64 + o0, H0 + c0, 64);
        mm_tile(a, wt + 16384 + 128 * 64 + o0, E + c0, 64);
    }

    // maxpool A: ch 64..255 = [h1, h0, center]
#pragma unroll
    for (int r = 1; r < 4; ++r) {
        int e = tid + r * 256;
        int ch = e >> 2, mloc = e & 3;
        int colb = mloc * 16;
        float v;
        if (ch < 128) {
            const float* row = E + (64 + (ch - 64)) * 64 + colb;
            v = row[0];
#pragma unroll
            for (int k = 1; k < 16; ++k) v = fmaxf(v, row[k]);
        } else if (ch < 192) {
            const float* row = H0 + (ch - 128) * 64 + colb;
            v = row[0];
#pragma unroll
            for (int k = 1; k < 16; ++k) v = fmaxf(v, row[k]);
        } else {
            v = E[(ch - 192) * 64 + colb];
        }
        out0[((b * 256 + ch) << 11) + m0 + mloc] = v;
    }
    __syncthreads();

    {   // write h2 over h1 rows
#pragma unroll
        for (int oo = 0; oo < 4; ++oo) {
            float4 v = make_float4(a[oo][0], a[oo][1], a[oo][2], a[oo][3]);
            *(float4*)(E + (64 + o0 + oo) * 64 + c0) = v;
        }
    }
    __syncthreads();

    {   // maxpool B: ch 0..63 = h2
        int ch = tid >> 2, mloc = tid & 3;
        int colb = mloc * 16;
        const float* row = E + (64 + ch) * 64 + colb;
        float v = row[0];
#pragma unroll
        for (int k = 1; k < 16; ++k) v = fmaxf(v, row[k]);
        out0[((b * 256 + ch) << 11) + m0 + mloc] = v;
    }
}

extern "C" void kernel_launch(void* const* d_in, const int* in_sizes, int n_in,
                              void* d_out, int out_size, void* d_ws, size_t ws_size,
                              hipStream_t stream) {
    const float* x   = (const float*)d_in[0];
    const float* xyz = (const float*)d_in[1];
    const float* W0  = (const float*)d_in[2];
    const float* b0  = (const float*)d_in[3];
    const float* W1  = (const float*)d_in[4];
    const float* b1  = (const float*)d_in[5];
    const float* W2  = (const float*)d_in[6];
    const float* b2  = (const float*)d_in[7];

    float* out  = (float*)d_out;                 // FLOAT32 output buffer
    float* out0 = out;                           // y: 4*256*2048
    float* out1 = out + 4 * 256 * 2048;          // sampled_xyz: 4*3*2048
    float* out2 = out1 + 4 * 3 * 2048;           // sampled_idx (f32): 4*2048
    u32*   flags = (u32*)out0;                   // progress[4] + pnorm_done

    char* ws = (char*)d_ws;
    u16*   idx_ws   = (u16*)ws;                  // 16384 B
    u16*   nbr_ws   = (u16*)(ws + 16384);        // 262144 B
    float* pnorm_ws = (float*)(ws + 278528);     // 131072 B
    float* wt_ws    = (float*)(ws + 409600);     // 114688 B

    init_kernel<<<1, 64, 0, stream>>>(flags);
    mega_kernel<<<380, 512, 0, stream>>>(xyz, x, W0, W1, W2,
                                         idx_ws, pnorm_ws, wt_ws,
                                         out1, out2, nbr_ws, flags);
    conv_kernel<<<2048, 256, 0, stream>>>(x, idx_ws, nbr_ws, wt_ws,
                                          b0, b1, b2, out0);
}

// Round 10
// 2438.932 us; speedup vs baseline: 1.4070x; 1.1701x over previous
//
#include <hip/hip_runtime.h>
#include <hip/hip_bf16.h>
#include <stdint.h>

typedef unsigned long long u64;
typedef unsigned int u32;
typedef unsigned short u16;

#define B_   4
#define C_   64
#define N_   8192
#define M_   2048
#define KNB  16
#define FLT_MAX_ 3.402823466e+38f
#define SMEM_SZ 87296   // 17408(pt)+256(spn)+69632(lists); >80KB -> 1 block/CU
#define NSPLIT 4        // knn N-scan split factor (tail: 676us -> ~170us)

__device__ __forceinline__ int clampN(int v) {
    return v < 0 ? 0 : (v > N_ - 1 ? N_ - 1 : v);
}

// ---------------- ws layout (bytes) — TOTAL 524288 ----------------
// idx_ws   : u16[B_*M_]       @ 0       (16384 B)
// nbr_ws   : u16[B_*M_*KNB]   @ 16384   (262144 B)
// pnorm_ws : float[B_*N_]     @ 278528  (131072 B)
// wt_ws    : float[448*64]    @ 409600  (114688 B)
// progress flags: u32[16] at out0[0..15]; knn PARTIALS (u64[8192*4*17],
// 4.46MB) at out0 + 1MB. Both are overwritten by conv's out0 stores at the
// end of each replay and re-initialized at the start -> no stale reliance.

__device__ __forceinline__ void pin4(float4& v) {
    asm volatile("" : "+v"(v.x), "+v"(v.y), "+v"(v.z), "+v"(v.w));
}

// DPP wave64 max -> returns wave max broadcast (via lane 63 readlane).
__device__ __forceinline__ float wave_fmax_dpp(float v) {
    float t;
    t = __int_as_float(__builtin_amdgcn_update_dpp(0, __float_as_int(v), 0x111, 0xf, 0xf, true)); v = fmaxf(v, t);
    t = __int_as_float(__builtin_amdgcn_update_dpp(0, __float_as_int(v), 0x112, 0xf, 0xf, true)); v = fmaxf(v, t);
    t = __int_as_float(__builtin_amdgcn_update_dpp(0, __float_as_int(v), 0x114, 0xf, 0xf, true)); v = fmaxf(v, t);
    t = __int_as_float(__builtin_amdgcn_update_dpp(0, __float_as_int(v), 0x118, 0xf, 0xf, true)); v = fmaxf(v, t);
    t = __int_as_float(__builtin_amdgcn_update_dpp(0, __float_as_int(v), 0x142, 0xa, 0xf, true)); v = fmaxf(v, t);
    t = __int_as_float(__builtin_amdgcn_update_dpp(0, __float_as_int(v), 0x143, 0xc, 0xf, true)); v = fmaxf(v, t);
    return __int_as_float(__builtin_amdgcn_readlane(__float_as_int(v), 63));
}

// np-exact FPS step (r7-r11: bit-exact 3-mul/2-add form, NO fma contraction).
#define FPS_STEP(PX, PY, PZ, DD, J)                                          \
    {                                                                        \
        float dx = __fsub_rn((PX), lx);                                      \
        float dy = __fsub_rn((PY), ly);                                      \
        float dz = __fsub_rn((PZ), lz);                                      \
        float d = __fadd_rn(__fadd_rn(__fmul_rn(dx, dx), __fmul_rn(dy, dy)), \
                            __fmul_rn(dz, dz));                              \
        float nd = fminf((DD), d);                                           \
        (DD) = nd;                                                           \
        bool gt = nd > fm;                                                   \
        fm = gt ? nd : fm;                                                   \
        fj = gt ? (J) : fj;                                                  \
        fx = gt ? (PX) : fx;                                                 \
        fy = gt ? (PY) : fy;                                                 \
        fz = gt ? (PZ) : fz;                                                 \
    }

__global__ void init_kernel(u32* __restrict__ flags) {
    if (threadIdx.x < 16) flags[threadIdx.x] = 0;
}

// ================== MEGA: fps + pnorm + wtrans + pipelined split-knn ========
// ROUND 22: r9 measured the tail — mega 2690 = fps 2014 + ONE knn block's
// 676us (group 63 ready only at fps end; 1 CU works, 255 idle). Fix: split
// each group's N-scan into NSPLIT=4 blocks (32 tiles each) writing partial
// top-17 u64 keys; tiny merge kernel 4-way-merges (keys unique -> order
// bit-identical to unsplit). knn block ids are GROUP-MAJOR so earliest-
// ready groups are resident first. Roles: 0-3 fps, 4-67 pnorm, 68-123
// wtrans, 124..1147 knn (grp-major x [b][split]).
__global__ __launch_bounds__(512, 2) void mega_kernel(
    const float* __restrict__ xyz, const float* __restrict__ x,
    const float* __restrict__ W0, const float* __restrict__ W1,
    const float* __restrict__ W2, u16* __restrict__ idx_ws,
    float* __restrict__ pnorm_ws, float* __restrict__ wt,
    float* __restrict__ out1, float* __restrict__ out2,
    u64* __restrict__ part, u32* __restrict__ flags) {
    const int bid = blockIdx.x;
    const int tid = threadIdx.x;
    __shared__ __align__(16) char SM[SMEM_SZ];

    if (bid < 4) {
        // ---------------- fps (r0 body) + hist + fused gather -------------
        const int b = bid;
        const int lane = tid & 63;
        const int w = tid >> 6;             // 8 waves
        const float* xb = xyz + b * 3 * N_;
        const int n0 = tid * 16;

        float4* red4 = (float4*)SM;          // [2][8] (256 B)
        int*    redi = (int*)(SM + 256);     // [2][8] (64 B)
        u16*    hist = (u16*)(SM + 320);     // [M_] (4096 B)

        float4 px[4], py[4], pz[4], dd[4];
#pragma unroll
        for (int j4 = 0; j4 < 4; ++j4) {
            px[j4] = *(const float4*)(xb + n0 + j4 * 4);
            py[j4] = *(const float4*)(xb + N_ + n0 + j4 * 4);
            pz[j4] = *(const float4*)(xb + 2 * N_ + n0 + j4 * 4);
            pin4(px[j4]); pin4(py[j4]); pin4(pz[j4]);
            dd[j4] = make_float4(FLT_MAX_, FLT_MAX_, FLT_MAX_, FLT_MAX_);
        }

        int cur = 0;
        float lx = xb[0], ly = xb[N_], lz = xb[2 * N_];
        if (tid == 0) { idx_ws[b * M_ + 0] = 0; hist[0] = 0; }

        for (int s = 1; s < M_; ++s) {
            float fm = -1.0f, fx = 0.f, fy = 0.f, fz = 0.f;
            int fj = 0;
#pragma unroll
            for (int j4 = 0; j4 < 4; ++j4) {
                FPS_STEP(px[j4].x, py[j4].x, pz[j4].x, dd[j4].x, j4 * 4 + 0);
                FPS_STEP(px[j4].y, py[j4].y, pz[j4].y, dd[j4].y, j4 * 4 + 1);
                FPS_STEP(px[j4].z, py[j4].z, pz[j4].z, dd[j4].z, j4 * 4 + 2);
                FPS_STEP(px[j4].w, py[j4].w, pz[j4].w, dd[j4].w, j4 * 4 + 3);
            }
            float wm = wave_fmax_dpp(fm);    // wave-uniform
            u64 bal = __ballot(fm == wm);    // >=1 bit set
            int winlane = (int)__ffsll(bal) - 1;
            const int par = s & 1;
            if (lane == winlane) {
                red4[(par << 3) + w] = make_float4(wm, fx, fy, fz);
                redi[(par << 3) + w] = n0 + fj;
            }
            __syncthreads();
            float4 p0 = red4[par << 3];
            float g = p0.x; float nlx = p0.y, nly = p0.z, nlz = p0.w;
            int ncur = redi[par << 3];
#pragma unroll
            for (int ww = 1; ww < 8; ++ww) {
                float4 p = red4[(par << 3) + ww];
                int id = redi[(par << 3) + ww];
                bool gt = p.x > g;           // strict: keeps first wave on ties
                g = gt ? p.x : g;
                nlx = gt ? p.y : nlx; nly = gt ? p.z : nly; nlz = gt ? p.w : nlz;
                ncur = gt ? id : ncur;
            }
            lx = nlx; ly = nly; lz = nlz; cur = ncur;
            if (tid == 0) {
                idx_ws[b * M_ + s] = (u16)cur; hist[s] = (u16)cur;
                if ((s & 63) == 63)   // amortized agent-release
                    __hip_atomic_store(&flags[b], (u32)s, __ATOMIC_RELEASE,
                                       __HIP_MEMORY_SCOPE_AGENT);
            }
            // single barrier per iter: next iter writes red4[par^1]
        }

        __syncthreads();                     // hist complete
        for (int m = tid; m < M_; m += 512) {
            int idx = (int)hist[m];
            out2[b * M_ + m] = (float)idx;
            out1[(b * 3 + 0) * M_ + m] = xb[idx];
            out1[(b * 3 + 1) * M_ + m] = xb[N_ + idx];
            out1[(b * 3 + 2) * M_ + m] = xb[2 * N_ + idx];
        }
        return;
    }

    if (bid < 68) {
        // ---------------- pnorm: blocks 4..67 ----------------
        int gid = (bid - 4) * 512 + tid;     // 0..32767
        int bb = gid >> 13, n = gid & 8191;
        const float* xb = x + bb * C_ * N_ + n;
        float acc = 0.f;
#pragma unroll 16
        for (int c = 0; c < C_; ++c) { float v = xb[c * N_]; acc = fmaf(v, v, acc); }
        pnorm_ws[gid] = acc;
        __syncthreads();                     // own stores drained
        if (tid == 0)
            __hip_atomic_fetch_add(&flags[4], 1u, __ATOMIC_RELEASE,
                                   __HIP_MEMORY_SCOPE_AGENT);
        return;
    }

    if (bid < 124) {
        // ---------------- wtrans: blocks 68..123 ----------------
        int e = (bid - 68) * 512 + tid;      // 0..28671
        if (e < 8192) {
            int i = e >> 6, o = e & 63;
            wt[e] = W0[o * 128 + i];
        } else if (e < 16384) {
            int e2 = e - 8192; int i = e2 >> 6, o = e2 & 63;
            wt[8192 + e2] = W1[o * 128 + i];
        } else {
            int e2 = e - 16384; int i = e2 >> 6, o = e2 & 63;
            wt[16384 + e2] = W2[o * 192 + i];
        }
        return;
    }

    // ------ knn: blocks 124..1147, grp-major: kid = ((grp*4)+b)*4 + split ---
    {
        const int kid = bid - 124;           // 0..1023
        const int grp = kid >> 4;            // 0..63  (ready order!)
        const int b   = (kid >> 2) & 3;
        const int sp  = kid & 3;
        const int m0  = grp * 32;

        float* pt    = (float*)SM;             // 64*68 floats (17408 B)
        float* spn   = (float*)(SM + 17408);   // 64 floats (256 B)
        u64*   lists = (u64*)(SM + 17664);     // 512*17 u64 (69632 B)

        if (tid == 0) {
            while (__hip_atomic_load(&flags[4], __ATOMIC_ACQUIRE,
                                     __HIP_MEMORY_SCOPE_AGENT) < 64u)
                __builtin_amdgcn_s_sleep(2);
            const u32 need = (u32)(m0 + 31);
            while (__hip_atomic_load(&flags[b], __ATOMIC_ACQUIRE,
                                     __HIP_MEMORY_SCOPE_AGENT) < need)
                __builtin_amdgcn_s_sleep(2);
        }
        __syncthreads();                       // idx/pnorm valid for this block

        const int q = tid & 31, sub = tid >> 5;   // sub 0..15
        const int m = m0 + q;
        const float* xb = x + b * C_ * N_;
        const int self = clampN((int)idx_ws[b * M_ + m]);

        float4 qv[16];
#pragma unroll
        for (int c4 = 0; c4 < 16; ++c4) {
            qv[c4].x = xb[(c4 * 4 + 0) * N_ + self];
            qv[c4].y = xb[(c4 * 4 + 1) * N_ + self];
            qv[c4].z = xb[(c4 * 4 + 2) * N_ + self];
            qv[c4].w = xb[(c4 * 4 + 3) * N_ + self];
        }
        const float qn = pnorm_ws[b * N_ + self];

        u64* L = lists + tid * 17;
#pragma unroll
        for (int j = 0; j < 17; ++j) L[j] = ~0ULL;
        u64 worst = ~0ULL;

        for (int t = sp * 32; t < sp * 32 + 32; ++t) {   // this split's tiles
            const int nb0 = t * 64;
            __syncthreads();
#pragma unroll
            for (int r = 0; r < 2; ++r) {
                int e = tid + r * 512;         // 0..1023 float4 units
                int c = e >> 4, nq = e & 15;
                float4 v = *(const float4*)(xb + c * N_ + nb0 + nq * 4);
                const int cs = c ^ (nq << 2);  // bank swizzle (r17)
                pt[(nq * 4 + 0) * 68 + cs] = v.x;
                pt[(nq * 4 + 1) * 68 + cs] = v.y;
                pt[(nq * 4 + 2) * 68 + cs] = v.z;
                pt[(nq * 4 + 3) * 68 + cs] = v.w;
            }
            if (tid < 64) spn[tid] = pnorm_ws[b * N_ + nb0 + tid];
            __syncthreads();
#pragma unroll
            for (int pp = 0; pp < 4; ++pp) {
                int nl = sub * 4 + pp;
                const float* pvbase = pt + nl * 68;
                const int rsw = (nl >> 2) << 2;
                float a0 = 0.f, a1 = 0.f, a2 = 0.f, a3 = 0.f;
#pragma unroll
                for (int c4 = 0; c4 < 16; ++c4) {
                    float4 p = *(const float4*)(pvbase + (((c4 << 2) ^ rsw)));
                    a0 = fmaf(qv[c4].x, p.x, a0);
                    a1 = fmaf(qv[c4].y, p.y, a1);
                    a2 = fmaf(qv[c4].z, p.z, a2);
                    a3 = fmaf(qv[c4].w, p.w, a3);
                }
                float dot = (a0 + a1) + (a2 + a3);
                float d = qn + spn[nl] - 2.0f * dot;
                u32 db = __float_as_uint(d);
                db = (db & 0x80000000u) ? ~db : (db | 0x80000000u);
                u64 key = ((u64)db << 32) | (u32)(nb0 + nl);
                if (key < worst) {
                    int j = 16;
                    while (j > 0 && L[j - 1] > key) { L[j] = L[j - 1]; --j; }
                    L[j] = key;
                    worst = L[16];
                }
            }
        }
        __syncthreads();
        if (tid < 32) {   // merge 16 sublists -> partial top-17 for query m
            int pos[16];
#pragma unroll
            for (int s2 = 0; s2 < 16; ++s2) pos[s2] = 0;
            u64* outp = part + (((u64)(b * M_ + m0 + tid)) * NSPLIT + sp) * 17;
            for (int r = 0; r < 17; ++r) {
                u64 best = ~0ULL; int bs = 0;
#pragma unroll
                for (int s2 = 0; s2 < 16; ++s2) {
                    u64 k2 = (pos[s2] < 17) ? lists[(tid + 32 * s2) * 17 + pos[s2]] : ~0ULL;
                    if (k2 < best) { best = k2; bs = s2; }
                }
#pragma unroll
                for (int s2 = 0; s2 < 16; ++s2) pos[s2] += (s2 == bs) ? 1 : 0;
                outp[r] = best;
            }
        }
    }
}

// ============ merge partial top-17s (4 sorted lists -> top-17, drop self) ===
__global__ __launch_bounds__(512) void knn_merge_kernel(const u64* __restrict__ part,
                                                        u16* __restrict__ nbr_ws) {
    int gid = blockIdx.x * 512 + threadIdx.x;   // 0..8191 = (b, m)
    const u64* p0 = part + ((u64)gid * NSPLIT + 0) * 17;
    const u64* p1 = p0 + 17;
    const u64* p2 = p1 + 17;
    const u64* p3 = p2 + 17;
    int i0 = 0, i1 = 0, i2 = 0, i3 = 0;
    u16* outp = nbr_ws + gid * KNB;
    for (int r = 0; r < 17; ++r) {
        u64 k0 = p0[i0], k1 = p1[i1], k2 = p2[i2], k3 = p3[i3];
        u64 ka = k0 < k1 ? k0 : k1;
        u64 kb = k2 < k3 ? k2 : k3;
        u64 best = ka < kb ? ka : kb;
        i0 += (best == k0) ? 1 : 0;
        i1 += (best == k1 && best != k0) ? 1 : 0;
        i2 += (best == k2 && best != k0 && best != k1) ? 1 : 0;
        i3 += (best == k3 && best != k0 && best != k1 && best != k2) ? 1 : 0;
        if (r > 0) outp[r - 1] = (u16)clampN((int)(best & 0xFFFFFFFFu));
    }
}

// =================== fused edge-conv x3 + k-maxpool (r6 verbatim) ==========
__device__ __forceinline__ void mm_tile(float a[4][4], const float* __restrict__ w,
                                        const float* __restrict__ s, int ni) {
#pragma unroll 8
    for (int i = 0; i < ni; ++i) {
        const float4 w4 = *(const float4*)(w + i * 64);
        const float4 e4 = *(const float4*)(s + i * 64);
        a[0][0] = fmaf(w4.x, e4.x, a[0][0]);
        a[0][1] = fmaf(w4.x, e4.y, a[0][1]);
        a[0][2] = fmaf(w4.x, e4.z, a[0][2]);
        a[0][3] = fmaf(w4.x, e4.w, a[0][3]);
        a[1][0] = fmaf(w4.y, e4.x, a[1][0]);
        a[1][1] = fmaf(w4.y, e4.y, a[1][1]);
        a[1][2] = fmaf(w4.y, e4.z, a[1][2]);
        a[1][3] = fmaf(w4.y, e4.w, a[1][3]);
        a[2][0] = fmaf(w4.z, e4.x, a[2][0]);
        a[2][1] = fmaf(w4.z, e4.y, a[2][1]);
        a[2][2] = fmaf(w4.z, e4.z, a[2][2]);
        a[2][3] = fmaf(w4.z, e4.w, a[2][3]);
        a[3][0] = fmaf(w4.w, e4.x, a[3][0]);
        a[3][1] = fmaf(w4.w, e4.y, a[3][1]);
        a[3][2] = fmaf(w4.w, e4.z, a[3][2]);
        a[3][3] = fmaf(w4.w, e4.w, a[3][3]);
    }
}

__global__ __launch_bounds__(256) void conv_kernel(const float* __restrict__ x,
                                                   const u16* __restrict__ idx_ws,
                                                   const u16* __restrict__ nbr_ws,
                                                   const float* __restrict__ wt,
                                                   const float* __restrict__ bias0,
                                                   const float* __restrict__ bias1,
                                                   const float* __restrict__ bias2,
                                                   float* __restrict__ out0) {
    __shared__ float E[128 * 64];    // rows 0..63 center; 64..127: nd -> h1 -> h2
    __shared__ float H0[64 * 64];

    const int tid = threadIdx.x;
    const int b = blockIdx.x >> 9;
    const int m0 = (blockIdx.x & 511) * 4;
    const float* xb = x + b * C_ * N_;

    {   // stage edge tile
        const int col = tid & 63;
        const int half = tid >> 6;
        const int m = m0 + (col >> 4);
        const int k = col & 15;
        const int selfm = clampN((int)idx_ws[b * M_ + m]);
        const int nbr = clampN((int)nbr_ws[(b * M_ + m) * KNB + k]);
#pragma unroll
        for (int c2 = 0; c2 < 16; ++c2) {
            int c = half * 16 + c2;
            float ctr = xb[c * N_ + selfm];
            float nb = xb[c * N_ + nbr];
            E[c * 64 + col] = ctr;
            E[(64 + c) * 64 + col] = __fsub_rn(nb, ctr);
        }
    }
    __syncthreads();

    const int o0 = (tid >> 4) * 4;
    const int c0 = (tid & 15) * 4;
    float a[4][4];

    {   // conv0 -> H0
        float4 bb = *(const float4*)(bias0 + o0);
        a[0][0] = a[0][1] = a[0][2] = a[0][3] = bb.x;
        a[1][0] = a[1][1] = a[1][2] = a[1][3] = bb.y;
        a[2][0] = a[2][1] = a[2][2] = a[2][3] = bb.z;
        a[3][0] = a[3][1] = a[3][2] = a[3][3] = bb.w;
        mm_tile(a, wt + o0, E + c0, 128);
#pragma unroll
        for (int oo = 0; oo < 4; ++oo) {
            float4 v = make_float4(fmaxf(a[oo][0], 0.f), fmaxf(a[oo][1], 0.f),
                                   fmaxf(a[oo][2], 0.f), fmaxf(a[oo][3], 0.f));
            *(float4*)(H0 + (o0 + oo) * 64 + c0) = v;
        }
    }
    __syncthreads();

    {   // conv1 -> h1 into E rows 64..127 (nd dead after conv0)
        float4 bb = *(const float4*)(bias1 + o0);
        a[0][0] = a[0][1] = a[0][2] = a[0][3] = bb.x;
        a[1][0] = a[1][1] = a[1][2] = a[1][3] = bb.y;
        a[2][0] = a[2][1] = a[2][2] = a[2][3] = bb.z;
        a[3][0] = a[3][1] = a[3][2] = a[3][3] = bb.w;
        mm_tile(a, wt + 8192 + o0, H0 + c0, 64);
        mm_tile(a, wt + 8192 + 64 * 64 + o0, E + c0, 64);
#pragma unroll
        for (int oo = 0; oo < 4; ++oo) {
            float4 v = make_float4(fmaxf(a[oo][0], 0.f), fmaxf(a[oo][1], 0.f),
                                   fmaxf(a[oo][2], 0.f), fmaxf(a[oo][3], 0.f));
            *(float4*)(E + (64 + o0 + oo) * 64 + c0) = v;
        }
    }
    __syncthreads();

    {   // conv2 (no relu), result held in regs until h1 maxpool done
        float4 bb = *(const float4*)(bias2 + o0);
        a[0][0] = a[0][1] = a[0][2] = a[0][3] = bb.x;
        a[1][0] = a[1][1] = a[1][2] = a[1][3] = bb.y;
        a[2][0] = a[2][1] = a[2][2] = a[2][3] = bb.z;
        a[3][0] = a[3][1] = a[3][2] = a[3][3] = bb.w;
        mm_tile(a, wt + 16384 + o0, E + 64 * 64 + c0, 64);
        mm_tile(a, wt + 16384 + 64 * 64 + o0, H0 + c0, 64);
        mm_tile(a, wt + 16384 + 128 * 64 + o0, E + c0, 64);
    }

    // maxpool A: ch 64..255 = [h1, h0, center]
#pragma unroll
    for (int r = 1; r < 4; ++r) {
        int e = tid + r * 256;
        int ch = e >> 2, mloc = e & 3;
        int colb = mloc * 16;
        float v;
        if (ch < 128) {
            const float* row = E + (64 + (ch - 64)) * 64 + colb;
            v = row[0];
#pragma unroll
            for (int k = 1; k < 16; ++k) v = fmaxf(v, row[k]);
        } else if (ch < 192) {
            const float* row = H0 + (ch - 128) * 64 + colb;
            v = row[0];
#pragma unroll
            for (int k = 1; k < 16; ++k) v = fmaxf(v, row[k]);
        } else {
            v = E[(ch - 192) * 64 + colb];
        }
        out0[((b * 256 + ch) << 11) + m0 + mloc] = v;
    }
    __syncthreads();

    {   // write h2 over h1 rows
#pragma unroll
        for (int oo = 0; oo < 4; ++oo) {
            float4 v = make_float4(a[oo][0], a[oo][1], a[oo][2], a[oo][3]);
            *(float4*)(E + (64 + o0 + oo) * 64 + c0) = v;
        }
    }
    __syncthreads();

    {   // maxpool B: ch 0..63 = h2
        int ch = tid >> 2, mloc = tid & 3;
        int colb = mloc * 16;
        const float* row = E + (64 + ch) * 64 + colb;
        float v = row[0];
#pragma unroll
        for (int k = 1; k < 16; ++k) v = fmaxf(v, row[k]);
        out0[((b * 256 + ch) << 11) + m0 + mloc] = v;
    }
}

extern "C" void kernel_launch(void* const* d_in, const int* in_sizes, int n_in,
                              void* d_out, int out_size, void* d_ws, size_t ws_size,
                              hipStream_t stream) {
    const float* x   = (const float*)d_in[0];
    const float* xyz = (const float*)d_in[1];
    const float* W0  = (const float*)d_in[2];
    const float* b0  = (const float*)d_in[3];
    const float* W1  = (const float*)d_in[4];
    const float* b1  = (const float*)d_in[5];
    const float* W2  = (const float*)d_in[6];
    const float* b2  = (const float*)d_in[7];

    float* out  = (float*)d_out;                 // FLOAT32 output buffer
    float* out0 = out;                           // y: 4*256*2048
    float* out1 = out + 4 * 256 * 2048;          // sampled_xyz: 4*3*2048
    float* out2 = out1 + 4 * 3 * 2048;           // sampled_idx (f32): 4*2048
    u32*   flags = (u32*)out0;                   // progress[4] + pnorm_done
    u64*   part  = (u64*)(out0 + 262144);        // partial top-17s (4.46 MB)

    char* ws = (char*)d_ws;
    u16*   idx_ws   = (u16*)ws;                  // 16384 B
    u16*   nbr_ws   = (u16*)(ws + 16384);        // 262144 B
    float* pnorm_ws = (float*)(ws + 278528);     // 131072 B
    float* wt_ws    = (float*)(ws + 409600);     // 114688 B

    init_kernel<<<1, 64, 0, stream>>>(flags);
    mega_kernel<<<1148, 512, 0, stream>>>(xyz, x, W0, W1, W2,
                                          idx_ws, pnorm_ws, wt_ws,
                                          out1, out2, part, flags);
    knn_merge_kernel<<<16, 512, 0, stream>>>(part, nbr_ws);
    conv_kernel<<<2048, 256, 0, stream>>>(x, idx_ws, nbr_ws, wt_ws,
                                          b0, b1, b2, out0);
}